// Round 12
// baseline (27021.057 us; speedup 1.0000x reference)
//
#include <hip/hip_runtime.h>

#define T_STEPS 32768
#define OUT_BASE 9830400  // 32768*300
#define RMASK 16383       // z1 ring = 16384 ticks (26.2 MB, in out-scratch)

typedef _Float16 h2 __attribute__((ext_vector_type(2)));
#define H2BC(f_) __builtin_bit_cast(h2, f_)

// relaxed/release agent-scope atomics (round-5/8/9-proven cross-XCD protocol)
#define ALD(p)     __hip_atomic_load((p), __ATOMIC_RELAXED, __HIP_MEMORY_SCOPE_AGENT)
#define AST(p, v)  __hip_atomic_store((p), (v), __ATOMIC_RELAXED, __HIP_MEMORY_SCOPE_AGENT)
#define ASTR(p, v) __hip_atomic_store((p), (v), __ATOMIC_RELEASE, __HIP_MEMORY_SCOPE_AGENT)
#define CFENCE()   asm volatile("" ::: "memory")

__device__ __forceinline__ float fdot2(h2 a, h2 b, float c) {
#if __has_builtin(__builtin_amdgcn_fdot2)
    return __builtin_amdgcn_fdot2(a, b, c, false);
#else
    return c + (float)a.x * (float)b.x + (float)a.y * (float)b.y;
#endif
}

__device__ __forceinline__ float sigf(float x) { return 1.f / (1.f + __expf(-x)); }

__device__ __forceinline__ float tanh_f(float x) {
    float a = fabsf(x);
    float e = __expf(-2.f * a);
    float t = (1.f - e) / (1.f + e);
    return x < 0.f ? -t : t;
}

// quad_perm DPP cross-lane read. CTRL: 0xB1=xor1, 0x4E=xor2.
template <int CTRL>
__device__ __forceinline__ float qperm(float x) {
#if __has_builtin(__builtin_amdgcn_update_dpp)
    return __builtin_bit_cast(
        float, __builtin_amdgcn_update_dpp(0, __builtin_bit_cast(int, x), CTRL, 0xF, 0xF, true));
#else
    return __shfl_xor(x, CTRL == 0xB1 ? 1 : 2);
#endif
}

// LDS-only barrier: keep global loads/stores (vmcnt) in flight across ticks.
__device__ __forceinline__ void bar_lds() {
    asm volatile("s_waitcnt lgkmcnt(0)\n\ts_barrier" ::: "memory");
}

// load 13 h2 (slice sg of a 100-float row: cols [26sg, 26sg+26), last slice 22
// cols zero-padded to 13 h2). 26*sg is even -> float2-aligned.
__device__ __forceinline__ void ldw13(h2* w, const float* rowp, int sg) {
    const float2* p = (const float2*)(rowp + 26 * sg);
    int n = (sg == 3) ? 11 : 13;
    for (int k = 0; k < 13; k++) {
        h2 t;
        if (k < n) { float2 v = p[k]; t.x = (_Float16)v.x; t.y = (_Float16)v.y; }
        else       { t.x = (_Float16)0.f; t.y = (_Float16)0.f; }
        w[k] = t;
    }
}

// Quad-slice MV: lane reads ITS 64B slice (3 x b128 + 1 x b32 = 52B used) and
// accumulates 4 gate rows x 13 h2, two chains per row (dep depth ~7).
// Declares s0_..s3_ = per-lane partials for gates i,f,g,o.
#define MVQ(REC_)                                                                            \
    float s0_, s1_, s2_, s3_;                                                                \
    {                                                                                        \
        const char* sp_ = (const char*)(REC_) + (sg << 6);                                   \
        float4 v0_ = *(const float4*)sp_;                                                    \
        float4 v1_ = *(const float4*)(sp_ + 16);                                             \
        float4 v2_ = *(const float4*)(sp_ + 32);                                             \
        float  v3_ = *(const float*)(sp_ + 48);                                              \
        h2 hs_[13] = {H2BC(v0_.x), H2BC(v0_.y), H2BC(v0_.z), H2BC(v0_.w),                    \
                      H2BC(v1_.x), H2BC(v1_.y), H2BC(v1_.z), H2BC(v1_.w),                    \
                      H2BC(v2_.x), H2BC(v2_.y), H2BC(v2_.z), H2BC(v2_.w),                    \
                      H2BC(v3_)};                                                            \
        float a_[4], b_[4];                                                                  \
        _Pragma("unroll") for (int g_ = 0; g_ < 4; g_++) { a_[g_] = 0.f; b_[g_] = 0.f; }     \
        _Pragma("unroll") for (int k_ = 0; k_ < 12; k_ += 2) {                               \
            _Pragma("unroll") for (int g_ = 0; g_ < 4; g_++) {                               \
                a_[g_] = fdot2(w[g_][k_],     hs_[k_],     a_[g_]);                          \
                b_[g_] = fdot2(w[g_][k_ + 1], hs_[k_ + 1], b_[g_]);                          \
            }                                                                                \
        }                                                                                    \
        _Pragma("unroll") for (int g_ = 0; g_ < 4; g_++)                                     \
            a_[g_] = fdot2(w[g_][12], hs_[12], a_[g_]);                                      \
        s0_ = a_[0] + b_[0]; s1_ = a_[1] + b_[1];                                            \
        s2_ = a_[2] + b_[2]; s3_ = a_[3] + b_[3];                                            \
    }

// butterfly: after this every lane of the quad holds ALL 4 full row sums,
// bitwise-identical across the quad (commutative pairwise adds).
#define BFLY4() do {                                                                         \
    s0_ += qperm<0xB1>(s0_); s1_ += qperm<0xB1>(s1_);                                        \
    s2_ += qperm<0xB1>(s2_); s3_ += qperm<0xB1>(s3_);                                        \
    s0_ += qperm<0x4E>(s0_); s1_ += qperm<0x4E>(s1_);                                        \
    s2_ += qperm<0x4E>(s2_); s3_ += qperm<0x4E>(s3_);                                        \
} while (0)

// ---------------- A0: Wc = W_ih_l0 @ W_inp  [400x300]; bc = W_ih_l0@b_inp + b_ih0 + b_hh0 ----------------
__global__ void k_precomp(const float* __restrict__ W_inp, const float* __restrict__ b_inp,
                          const float* __restrict__ W_ih0, const float* __restrict__ b_ih0,
                          const float* __restrict__ b_hh0,
                          float* __restrict__ Wc, float* __restrict__ bc) {
    int idx = blockIdx.x * 256 + threadIdx.x;
    if (idx < 120000) {
        int r = idx / 300, d = idx % 300;
        float acc = 0.f;
        for (int h = 0; h < 100; h++) acc += W_ih0[r * 100 + h] * W_inp[h * 300 + d];
        Wc[idx] = acc;
    } else if (idx < 120400) {
        int r = idx - 120000;
        float acc = b_ih0[r] + b_hh0[r];
        for (int h = 0; h < 100; h++) acc += W_ih0[r * 100 + h] * b_inp[h];
        bc[r] = acc;
    }
}

// ---------------- A1: x0p[t][u*4+g] = inputs[t] . Wc[g*100+u] + bc, stored f16 ----------------
__global__ __launch_bounds__(512) void k_xproj(const float* __restrict__ inp,
                                               const float* __restrict__ Wc,
                                               const float* __restrict__ bc,
                                               _Float16* __restrict__ x0p) {
    __shared__ float xs[32 * 300];
    int t0 = blockIdx.x * 32;
    for (int idx = threadIdx.x; idx < 9600; idx += 512) xs[idx] = inp[(size_t)t0 * 300 + idx];
    __syncthreads();
    int j = threadIdx.x;
    if (j < 400) {
        float acc[32];
#pragma unroll
        for (int i = 0; i < 32; i++) acc[i] = 0.f;
        const float4* w4 = (const float4*)(Wc + j * 300);
        const float4* x4 = (const float4*)xs;
        for (int d4 = 0; d4 < 75; d4++) {
            float4 w = w4[d4];
#pragma unroll
            for (int ti = 0; ti < 32; ti++) {
                float4 x = x4[ti * 75 + d4];
                acc[ti] += w.x * x.x + w.y * x.y + w.z * x.z + w.w * x.w;
            }
        }
        float bb = bc[j];
        int dst = (j % 100) * 4 + j / 100;
#pragma unroll
        for (int ti = 0; ti < 32; ti++)
            x0p[(size_t)(t0 + ti) * 400 + dst] = (_Float16)(acc[ti] + bb);
    }
}

// ================= Three-CU scan, quad-slice all-gates layout =================
// grid=3 cooperative, 512 thr (8 waves even {2,2,2,2}, waves_per_eu(2,2) ->
// proven 128-reg budget). Lane j<400: unit u=j>>2, slice sg=j&3.
// LDS record = 4 slices x 64B = 256B (64 u32); h element e at f16 idx
// (e/26)*32 + e%26; slice pads stay zero. Reads: 4 instrs/lane (vs 7) and
// 7 MV waves -> 28 LDS instrs/tick (round-9: 49 -- the measured limiter).
// x/z/bias are injected PRE-reduce into partial sg (fmaf with lane masks);
// the xor1+xor2 butterfly then distributes all 4 completed gates to all 4
// lanes -> no gather chain; every lane updates c redundantly; sg==0 writes.
// Protocol/flags/ring: round-9 verbatim.
// flags[]: [0]=h0 progress  [1]=z tiles done  [2]=B2 progress (backpressure)

#define B0TICK(T_, XR_, P_) do {                                                             \
    if (j < 400) {                                                                           \
        float xf_ = (float)XR_;                                                              \
        int tn_ = (T_) + 2 < T_STEPS ? (T_) + 2 : T_STEPS - 1;                               \
        XR_ = x0p[(size_t)tn_ * 400 + j];                                                    \
        MVQ(lds + (P_) * 64);                                                                \
        s0_ = __builtin_fmaf(m0, xf_, s0_); s1_ = __builtin_fmaf(m1, xf_, s1_);              \
        s2_ = __builtin_fmaf(m2, xf_, s2_); s3_ = __builtin_fmaf(m3, xf_, s3_);              \
        BFLY4();                                                                             \
        float si_ = sigf(s0_), sf_ = sigf(s1_), tg_ = tanh_f(s2_), so_ = sigf(s3_);          \
        c0 = sf_ * c0 + si_ * tg_;                                                           \
        float hv_ = so_ * tanh_f(c0);                                                        \
        if (sg == 0) {                                                                       \
            ((_Float16*)(lds + (1 - (P_)) * 64))[hpos] = (_Float16)hv_;                      \
            if ((T_) == T_STEPS - 1) { outTail[u] = hv_; outTail[200 + u] = c0; }            \
        }                                                                                    \
    } else if (j >= 448) {                                                                   \
        if (kk < 50 && (T_) >= 1)                                                            \
            AST(&h0seq[(size_t)((T_) - 1) * 50 + kk], (lds + (P_) * 64)[hp2]);               \
        if (kk == 0 && (((T_) & 7) == 7)) ASTR(&flags[0], (unsigned)(T_));                   \
    }                                                                                        \
    bar_lds();                                                                               \
} while (0)

#define B2TICK(T_, ZR_, P_) do {                                                             \
    if (j < 400) {                                                                           \
        float zf_ = ZR_;                                                                     \
        int tn_ = (T_) + 2 < T_STEPS ? (T_) + 2 : T_STEPS - 1;                               \
        ZR_ = ALD(&z1ring[(size_t)(tn_ & RMASK) * 400 + j]);                                 \
        MVQ(lds + (P_) * 64);                                                                \
        s0_ = __builtin_fmaf(m0, zf_, s0_); s1_ = __builtin_fmaf(m1, zf_, s1_);              \
        s2_ = __builtin_fmaf(m2, zf_, s2_); s3_ = __builtin_fmaf(m3, zf_, s3_);              \
        BFLY4();                                                                             \
        float si_ = sigf(s0_), sf_ = sigf(s1_), tg_ = tanh_f(s2_), so_ = sigf(s3_);          \
        c1 = sf_ * c1 + si_ * tg_;                                                           \
        float hv_ = so_ * tanh_f(c1);                                                        \
        if (sg == 0) {                                                                       \
            ((_Float16*)(lds + (1 - (P_)) * 64))[hpos] = (_Float16)hv_;                      \
            h1s[(size_t)(T_) * 100 + u] = hv_;                                               \
            if ((T_) == T_STEPS - 1) { outTail[100 + u] = hv_; outTail[300 + u] = c1; }      \
        }                                                                                    \
    } else if (j == 448) {                                                                   \
        int tq_ = (T_) + 3 < T_STEPS ? (T_) + 3 : T_STEPS - 1;                               \
        unsigned need_ = (unsigned)(tq_ >> 4) + 1u;                                          \
        if (zdc < need_) {                                                                   \
            while ((zdc = ALD(&flags[1])) < need_) __builtin_amdgcn_s_sleep(2);              \
            CFENCE();                                                                        \
        }                                                                                    \
        if (((T_) & 255) == 255) ASTR(&flags[2], (unsigned)(T_) + 1u);                       \
    }                                                                                        \
    bar_lds();                                                                               \
} while (0)

__global__ __launch_bounds__(512) __attribute__((amdgpu_waves_per_eu(2, 2)))
void k_scan3(const _Float16* __restrict__ x0p,
             const float* __restrict__ Whh0,
             const float* __restrict__ Wih1,
             const float* __restrict__ Whh1,
             const float* __restrict__ bih1,
             const float* __restrict__ bhh1,
             float* __restrict__ h1s,
             float* __restrict__ outTail,
             unsigned* __restrict__ h0seq,
             float* __restrict__ z1ring,
             unsigned* __restrict__ flags) {
    // B0/B2: 2 records (double buffer) = 128 u32. Bz: 16 records = 1024 u32.
    __shared__ __align__(16) unsigned lds[1024];
    const int j = threadIdx.x;
    const int u = (j >> 2), sg = j & 3;
    const int hpos = (u / 26) * 32 + (u % 26);  // f16 idx of h[u] in a record
    const int kk = j - 448;
    const int e2 = 2 * (kk < 0 ? 0 : (kk > 49 ? 49 : kk));
    const int hp2 = (e2 / 26) * 16 + (e2 % 26) / 2;  // u32 idx of pair kk
    const float m0 = (sg == 0) ? 1.f : 0.f, m1 = (sg == 1) ? 1.f : 0.f;
    const float m2 = (sg == 2) ? 1.f : 0.f, m3 = (sg == 3) ? 1.f : 0.f;

    if (blockIdx.x == 0) {
        // ---------------- B0: layer-0 scan ----------------
        h2 w[4][13];
        _Float16 xa = (_Float16)0.f, xb = (_Float16)0.f;
        float c0 = 0.f;
        if (j < 400) {
#pragma unroll
            for (int g = 0; g < 4; g++) ldw13(w[g], Whh0 + (g * 100 + u) * 100, sg);
            xa = x0p[j];          // x(0): layout u*4+g == j
            xb = x0p[400 + j];    // x(1)
        }
        if (j < 128) lds[j] = 0u;  // h0(-1)=0 + pads, both buffers
        __syncthreads();

        for (int t = 0; t < T_STEPS; t += 2) {
            B0TICK(t, xa, 0);
            B0TICK(t + 1, xb, 1);
        }
        if (j >= 448) {  // publish h0(T-1) (sits in buffer 0) + final flag
            if (kk < 50) AST(&h0seq[(size_t)(T_STEPS - 1) * 50 + kk], lds[hp2]);
            if (kk == 0) ASTR(&flags[0], (unsigned)T_STEPS);
        }
    } else if (blockIdx.x == 1) {
        // ---------------- Bz: z1 = W_ih1.h0 + b1 streaming GEMM, 16-tick tiles ----------------
        h2 w[4][13];
        float bz = 0.f;
        if (j < 400) {
#pragma unroll
            for (int g = 0; g < 4; g++) ldw13(w[g], Wih1 + (g * 100 + u) * 100, sg);
            int ro = sg * 100 + u;  // own gate row (for the pre-reduce bias inject)
            bz = bih1[ro] + bhh1[ro];
        }
        for (int idx = j; idx < 1024; idx += 512) lds[idx] = 0u;
        __syncthreads();

        unsigned fcache = 0, bpc = 0;
        for (int tau = 0; tau < 2048; ++tau) {
            const int t0 = tau * 16;
            while (fcache < (unsigned)(t0 + 16)) {
                fcache = ALD(&flags[0]);
                if (fcache < (unsigned)(t0 + 16)) __builtin_amdgcn_s_sleep(8);
            }
            int lim = t0 + 32 - (RMASK + 1);  // ring backpressure (round-7 fix)
            if (lim > 0) {
                while ((int)bpc < lim) {
                    bpc = ALD(&flags[2]);
                    if ((int)bpc < lim) __builtin_amdgcn_s_sleep(8);
                }
            }
            CFENCE();
            // stage 800 packed pairs -> 16 records (pair e=2k never straddles a
            // slice: slices start at even cols 0/26/52/78)
            for (int g = j; g < 800; g += 512) {
                int tt = g / 50, k = g % 50;
                int e = 2 * k;
                lds[tt * 64 + (e / 26) * 16 + (e % 26) / 2] =
                    ALD(&h0seq[(size_t)t0 * 50 + g]);
            }
            __syncthreads();
            if (j < 400) {
                for (int tt = 0; tt < 16; ++tt) {
                    MVQ(lds + tt * 64);
                    s0_ = __builtin_fmaf(m0, bz, s0_); s1_ = __builtin_fmaf(m1, bz, s1_);
                    s2_ = __builtin_fmaf(m2, bz, s2_); s3_ = __builtin_fmaf(m3, bz, s3_);
                    BFLY4();
                    float zo_ = sg == 0 ? s0_ : (sg == 1 ? s1_ : (sg == 2 ? s2_ : s3_));
                    AST((unsigned*)&z1ring[(size_t)((t0 + tt) & RMASK) * 400 + j],
                        __builtin_bit_cast(unsigned, zo_));
                }
            }
            __syncthreads();  // per-wave vmcnt(0) drain -> all z stores complete
            if (j == 0) ASTR(&flags[1], (unsigned)(tau + 1));
        }
    } else {
        // ---------------- B2: layer-1 scan ----------------
        h2 w[4][13];
        float za = 0.f, zb = 0.f, c1 = 0.f;
        unsigned zdc = 0;
        if (j < 400) {
#pragma unroll
            for (int g = 0; g < 4; g++) ldw13(w[g], Whh1 + (g * 100 + u) * 100, sg);
        }
        if (j < 128) lds[j] = 0u;  // h1(-1)=0 + pads
        __syncthreads();
        if (j == 448) {  // wait for z tile 0 (ticks 0..15)
            while ((zdc = ALD(&flags[1])) < 1u) __builtin_amdgcn_s_sleep(8);
            CFENCE();
        }
        __syncthreads();
        if (j < 400) {
            za = __builtin_bit_cast(float, ALD((const unsigned*)&z1ring[j]));        // z(0)
            zb = __builtin_bit_cast(float, ALD((const unsigned*)&z1ring[400 + j]));  // z(1)
        }

        for (int t = 0; t < T_STEPS; t += 2) {
            B2TICK(t, za, 0);      // use z(t); prefetch za=z(t+2)
            B2TICK(t + 1, zb, 1);  // use z(t+1); prefetch zb=z(t+3)
        }
    }
}

// ---------------- C: outputs[t][d] = h1s[t] . W_out[d] + b_out[d] ----------------
__global__ __launch_bounds__(320) void k_out(const float* __restrict__ h1s,
                                             const float* __restrict__ Wout,
                                             const float* __restrict__ bout,
                                             float* __restrict__ out) {
    __shared__ float hs[32 * 100];
    int t0 = blockIdx.x * 32;
    for (int idx = threadIdx.x; idx < 3200; idx += 320) hs[idx] = h1s[(size_t)t0 * 100 + idx];
    __syncthreads();
    int d = threadIdx.x;
    if (d < 300) {
        float acc[32];
#pragma unroll
        for (int i = 0; i < 32; i++) acc[i] = 0.f;
        const float4* w4 = (const float4*)(Wout + d * 100);
        const float4* h4 = (const float4*)hs;
        for (int j4 = 0; j4 < 25; j4++) {
            float4 w = w4[j4];
#pragma unroll
            for (int ti = 0; ti < 32; ti++) {
                float4 h = h4[ti * 25 + j4];
                acc[ti] += w.x * h.x + w.y * h.y + w.z * h.z + w.w * h.w;
            }
        }
        float bb = bout[d];
#pragma unroll
        for (int ti = 0; ti < 32; ti++) out[(size_t)(t0 + ti) * 300 + d] = acc[ti] + bb;
    }
}

extern "C" void kernel_launch(void* const* d_in, const int* in_sizes, int n_in,
                              void* d_out, int out_size, void* d_ws, size_t ws_size,
                              hipStream_t stream) {
    const float* inputs = (const float*)d_in[0];
    const float* W_inp  = (const float*)d_in[1];
    const float* b_inp  = (const float*)d_in[2];
    const float* W_ih0  = (const float*)d_in[3];
    const float* W_hh0  = (const float*)d_in[4];
    const float* b_ih0  = (const float*)d_in[5];
    const float* b_hh0  = (const float*)d_in[6];
    const float* W_ih1  = (const float*)d_in[7];
    const float* W_hh1  = (const float*)d_in[8];
    const float* b_ih1  = (const float*)d_in[9];
    const float* b_hh1  = (const float*)d_in[10];
    const float* W_out  = (const float*)d_in[11];
    const float* b_out  = (const float*)d_in[12];
    float* out = (float*)d_out;

    char* ws = (char*)d_ws;
    _Float16* x0p = (_Float16*)ws;                    // 32768*400*2 = 26,214,400 B
    float* h1s = (float*)(ws + 26214400);             // 32768*100*4 = 13,107,200 B
    float* Wc  = (float*)(ws + 26214400 + 13107200);  // 400*300*4   =    480,000 B
    float* bc  = Wc + 120000;                         // 400*4 B

    // out-scratch region [0, OUT_BASE*4): fully overwritten by k_out afterwards.
    //   z1ring: 16384*400*4 = 26,214,400 B  @ 0
    //   h0seq : 32768*50*4  =  6,553,600 B  @ 26,214,400
    //   flags : 3 u32                       @ 32,768,000   (all < 39,321,600)
    float*    z1ring = out;
    unsigned* h0seq  = (unsigned*)((char*)out + 26214400);
    unsigned* flagsp = (unsigned*)((char*)out + 32768000);
    float*    outTail = out + OUT_BASE;

    hipMemsetAsync(flagsp, 0, 16, stream);
    k_precomp<<<471, 256, 0, stream>>>(W_inp, b_inp, W_ih0, b_ih0, b_hh0, Wc, bc);
    k_xproj<<<1024, 512, 0, stream>>>(inputs, Wc, bc, x0p);

    void* args[] = {(void*)&x0p, (void*)&W_hh0, (void*)&W_ih1, (void*)&W_hh1,
                    (void*)&b_ih1, (void*)&b_hh1, (void*)&h1s, (void*)&outTail,
                    (void*)&h0seq, (void*)&z1ring, (void*)&flagsp};
    hipLaunchCooperativeKernel((void*)k_scan3, dim3(3), dim3(512), args, 0, stream);

    k_out<<<1024, 320, 0, stream>>>(h1s, W_out, b_out, out);
}

// Round 13
// 26882.065 us; speedup vs baseline: 1.0052x; 1.0052x over previous
//
#include <hip/hip_runtime.h>

#define T_STEPS 32768
#define OUT_BASE 9830400  // 32768*300
#define RMASK 16383       // z1 ring = 16384 ticks (26.2 MB, in out-scratch)

typedef _Float16 h2 __attribute__((ext_vector_type(2)));
typedef _Float16 f16x8 __attribute__((ext_vector_type(8)));
typedef float f32x4 __attribute__((ext_vector_type(4)));
#define H2BC(f_) __builtin_bit_cast(h2, f_)

// relaxed/release agent-scope atomics (round-5/8/9-proven cross-XCD protocol)
#define ALD(p)     __hip_atomic_load((p), __ATOMIC_RELAXED, __HIP_MEMORY_SCOPE_AGENT)
#define AST(p, v)  __hip_atomic_store((p), (v), __ATOMIC_RELAXED, __HIP_MEMORY_SCOPE_AGENT)
#define ASTR(p, v) __hip_atomic_store((p), (v), __ATOMIC_RELEASE, __HIP_MEMORY_SCOPE_AGENT)
#define CFENCE()   asm volatile("" ::: "memory")

#define MFMA16(A_, B_, C_) __builtin_amdgcn_mfma_f32_16x16x32_f16(A_, B_, C_, 0, 0, 0)

__device__ __forceinline__ float fdot2(h2 a, h2 b, float c) {
#if __has_builtin(__builtin_amdgcn_fdot2)
    return __builtin_amdgcn_fdot2(a, b, c, false);
#else
    return c + (float)a.x * (float)b.x + (float)a.y * (float)b.y;
#endif
}

__device__ __forceinline__ float sigf(float x) { return 1.f / (1.f + __expf(-x)); }

__device__ __forceinline__ float tanh_f(float x) {
    float a = fabsf(x);
    float e = __expf(-2.f * a);
    float t = (1.f - e) / (1.f + e);
    return x < 0.f ? -t : t;
}

// quad_perm DPP cross-lane read (Bz half-combine). 0xB1 = xor1.
template <int CTRL>
__device__ __forceinline__ float qperm(float x) {
#if __has_builtin(__builtin_amdgcn_update_dpp)
    return __builtin_bit_cast(
        float, __builtin_amdgcn_update_dpp(0, __builtin_bit_cast(int, x), CTRL, 0xF, 0xF, true));
#else
    return __shfl_xor(x, 1);
#endif
}

// LDS-only barrier: keep global loads/stores (vmcnt) in flight across ticks.
__device__ __forceinline__ void bar_lds() {
    asm volatile("s_waitcnt lgkmcnt(0)\n\ts_barrier" ::: "memory");
}

// load 25 f16-pairs of one row-half (50 consecutive floats) into h2 regs (Bz)
__device__ __forceinline__ void ldw(h2* w, const float* p) {
#pragma unroll
    for (int k = 0; k < 25; k++) {
        float2 v = ((const float2*)p)[k];
        h2 t; t.x = (_Float16)v.x; t.y = (_Float16)v.y; w[k] = t;
    }
}

// Bz half-row MV: 25 h2 from rec (6 x b128 + 1 x b32) x two rows (round-9 verbatim)
__device__ __forceinline__ float2 mv25(const h2* wA, const h2* wB, const char* rec) {
    const float4* hv = (const float4*)rec;
    float pA = 0.f, pB = 0.f;
#pragma unroll
    for (int c = 0; c < 6; c++) {
        float4 v = hv[c];
        pA = fdot2(wA[4 * c + 0], H2BC(v.x), pA); pB = fdot2(wB[4 * c + 0], H2BC(v.x), pB);
        pA = fdot2(wA[4 * c + 1], H2BC(v.y), pA); pB = fdot2(wB[4 * c + 1], H2BC(v.y), pB);
        pA = fdot2(wA[4 * c + 2], H2BC(v.z), pA); pB = fdot2(wB[4 * c + 2], H2BC(v.z), pB);
        pA = fdot2(wA[4 * c + 3], H2BC(v.w), pA); pB = fdot2(wB[4 * c + 3], H2BC(v.w), pB);
    }
    float vl = *(const float*)(rec + 96);
    pA = fdot2(wA[24], H2BC(vl), pA); pB = fdot2(wB[24], H2BC(vl), pB);
    return make_float2(pA, pB);
}

// MFMA A-fragment pack: lane (col, grp) of tile -> 8 f16 of permuted row
// r' = 16*tile + col (unit u=r'>>2, gate g=r'&3 -> orig row g*100+u),
// cols k = kt*32 + grp*8 + j (zero-padded past 100).
__device__ __forceinline__ void packA(f16x8* wf, const float* W, int tile, int col, int grp) {
    int rp = 16 * tile + col;
    const float* wr = W + ((rp & 3) * 100 + (rp >> 2)) * 100;
#pragma unroll
    for (int kt = 0; kt < 4; kt++) {
        f16x8 a;
#pragma unroll
        for (int jj = 0; jj < 8; jj++) {
            int k = kt * 32 + grp * 8 + jj;
            a[jj] = (k < 100) ? (_Float16)wr[k] : (_Float16)0.f;
        }
        wf[kt] = a;
    }
}

__device__ __forceinline__ f32x4 xcvt(unsigned long long v) {
    h2 p0 = __builtin_bit_cast(h2, (unsigned)(v & 0xffffffffu));
    h2 p1 = __builtin_bit_cast(h2, (unsigned)(v >> 32));
    f32x4 r; r[0] = (float)p0.x; r[1] = (float)p0.y; r[2] = (float)p1.x; r[3] = (float)p1.y;
    return r;
}

// ---------------- A0: Wc = W_ih_l0 @ W_inp  [400x300]; bc = W_ih_l0@b_inp + b_ih0 + b_hh0 ----------------
__global__ void k_precomp(const float* __restrict__ W_inp, const float* __restrict__ b_inp,
                          const float* __restrict__ W_ih0, const float* __restrict__ b_ih0,
                          const float* __restrict__ b_hh0,
                          float* __restrict__ Wc, float* __restrict__ bc) {
    int idx = blockIdx.x * 256 + threadIdx.x;
    if (idx < 120000) {
        int r = idx / 300, d = idx % 300;
        float acc = 0.f;
        for (int h = 0; h < 100; h++) acc += W_ih0[r * 100 + h] * W_inp[h * 300 + d];
        Wc[idx] = acc;
    } else if (idx < 120400) {
        int r = idx - 120000;
        float acc = b_ih0[r] + b_hh0[r];
        for (int h = 0; h < 100; h++) acc += W_ih0[r * 100 + h] * b_inp[h];
        bc[r] = acc;
    }
}

// ---------------- A1: x0p[t][u*4+g] = inputs[t] . Wc[g*100+u] + bc, stored f16 ----------------
__global__ __launch_bounds__(512) void k_xproj(const float* __restrict__ inp,
                                               const float* __restrict__ Wc,
                                               const float* __restrict__ bc,
                                               _Float16* __restrict__ x0p) {
    __shared__ float xs[32 * 300];
    int t0 = blockIdx.x * 32;
    for (int idx = threadIdx.x; idx < 9600; idx += 512) xs[idx] = inp[(size_t)t0 * 300 + idx];
    __syncthreads();
    int j = threadIdx.x;
    if (j < 400) {
        float acc[32];
#pragma unroll
        for (int i = 0; i < 32; i++) acc[i] = 0.f;
        const float4* w4 = (const float4*)(Wc + j * 300);
        const float4* x4 = (const float4*)xs;
        for (int d4 = 0; d4 < 75; d4++) {
            float4 w = w4[d4];
#pragma unroll
            for (int ti = 0; ti < 32; ti++) {
                float4 x = x4[ti * 75 + d4];
                acc[ti] += w.x * x.x + w.y * x.y + w.z * x.z + w.w * x.w;
            }
        }
        float bb = bc[j];
        int dst = (j % 100) * 4 + j / 100;
#pragma unroll
        for (int ti = 0; ti < 32; ti++)
            x0p[(size_t)(t0 + ti) * 400 + dst] = (_Float16)(acc[ti] + bb);
    }
}

// ================= Three-CU MFMA scan =================
// grid=3 cooperative, 512 thr (8 waves, waves_per_eu(2,2) -> proven 256 budget).
//   B0: layer-0 scan via MFMA; publishes h0seq + flags[0] (round-9 protocol).
//   Bz: z1 = W_ih1.h0 + b1 streaming GEMM (round-9 VERBATIM, fdot2).
//   B2: layer-1 scan via MFMA; C-init = z1ring (dist-2 prefetch); flags[2] beacon.
// MFMA mapping (16x16x32 f16, rows packed r'=4u+g):
//   A: lane holds row l&15 of its tile, k = kt*32 + (l>>4)*8 + j (4 frags resident).
//   B: h(t-1) record in LDS (128 f16, zero-padded), replicated over all 16 cols ->
//      per-kt read = ds_read_b128 at kt*64 + (l>>4)*16 (broadcast in 16-lane groups).
//   D: col=l&15 (redundant), row=(l>>4)*4+reg -> lane's 4 regs = gates i,f,g,o of
//      unit 4*tile + (l>>4). Lane-local LSTM update, NO cross-lane gather.
// Tiles: 25 (units 4t..4t+3); wave w owns {w, w+8, w+16} (+24 for w=0).
// NL distribution: lane processes tile idx=min(l&3,nt-1) -> 4x less redundant NL;
// writer lanes (l&15)<4 (dup writes for 3-tile waves are same-value, benign).
// flags[]: [0]=h0 progress  [1]=z tiles done  [2]=B2 progress (backpressure)

#define CHAIN4(ACC_, WF_) do {                                                               \
    ACC_ = MFMA16(WF_[0], hf0, ACC_); ACC_ = MFMA16(WF_[1], hf1, ACC_);                      \
    ACC_ = MFMA16(WF_[2], hf2, ACC_); ACC_ = MFMA16(WF_[3], hf3, ACC_);                      \
} while (0)

// common per-tick MFMA/NL body; CINIT0_.. are f32x4 C-inits, CS_ the cell state
#define SCAN_CORE(P_, CI0_, CI1_, CI2_, CI3_, CS_, HV_) do {                                 \
    const char* rb_ = (const char*)lds + (P_) * 256;                                         \
    f16x8 hf0 = *(const f16x8*)(rb_ + grp * 16);                                             \
    f16x8 hf1 = *(const f16x8*)(rb_ + 64 + grp * 16);                                        \
    f16x8 hf2 = *(const f16x8*)(rb_ + 128 + grp * 16);                                       \
    f16x8 hf3 = *(const f16x8*)(rb_ + 192 + grp * 16);                                       \
    f32x4 a0_ = CI0_, a1_ = CI1_, a2_ = CI2_;                                                \
    CHAIN4(a0_, w0); CHAIN4(a1_, w1); CHAIN4(a2_, w2);                                       \
    f32x4 gv_;                                                                               \
    if (wid == 0) {                                                                          \
        f32x4 a3_ = CI3_;                                                                    \
        CHAIN4(a3_, w3);                                                                     \
        gv_ = (lsel == 0) ? a0_ : ((lsel == 1) ? a1_ : ((lsel == 2) ? a2_ : a3_));           \
    } else {                                                                                 \
        gv_ = (lsel == 0) ? a0_ : ((lsel == 1) ? a1_ : a2_);                                 \
    }                                                                                        \
    float si_ = sigf(gv_[0]), sf_ = sigf(gv_[1]);                                            \
    float tg_ = tanh_f(gv_[2]), so_ = sigf(gv_[3]);                                          \
    CS_ = sf_ * CS_ + si_ * tg_;                                                             \
    HV_ = so_ * tanh_f(CS_);                                                                 \
    if ((l & 15) < 4)                                                                        \
        ((_Float16*)((char*)lds + (1 - (P_)) * 256))[uS] = (_Float16)HV_;                    \
} while (0)

__global__ __launch_bounds__(512) __attribute__((amdgpu_waves_per_eu(2, 2)))
void k_scan3(const _Float16* __restrict__ x0p,
             const float* __restrict__ Whh0,
             const float* __restrict__ Wih1,
             const float* __restrict__ Whh1,
             const float* __restrict__ bih1,
             const float* __restrict__ bhh1,
             float* __restrict__ h1s,
             float* __restrict__ outTail,
             unsigned* __restrict__ h0seq,
             float* __restrict__ z1ring,
             unsigned* __restrict__ flags) {
    // B0/B2: 2 records x 256B = 128 u32. Bz: 16 x 56-u32 records (R9 verbatim).
    __shared__ __align__(16) unsigned lds[896];
    const int j = threadIdx.x;

    if (blockIdx.x == 0) {
        // ---------------- B0: layer-0 MFMA scan ----------------
        const int wid = j >> 6, l = j & 63, col = l & 15, grp = l >> 4, lsel = l & 3;
        const int t0_ = wid, t1_ = wid + 8, t2_ = wid + 16;
        const int uD0 = 4 * t0_ + grp, uD1 = 4 * t1_ + grp, uD2 = 4 * t2_ + grp;
        const int uD3 = 96 + grp;  // tile 24 (wave 0 only)
        int tsel;
        if (wid == 0) tsel = (lsel == 0) ? t0_ : ((lsel == 1) ? t1_ : ((lsel == 2) ? t2_ : 24));
        else          tsel = (lsel == 0) ? t0_ : ((lsel == 1) ? t1_ : t2_);
        const int uS = 4 * tsel + grp;

        f16x8 w0[4], w1[4], w2[4], w3[4];
        packA(w0, Whh0, t0_, col, grp);
        packA(w1, Whh0, t1_, col, grp);
        packA(w2, Whh0, t2_, col, grp);
        packA(w3, Whh0, (wid == 0) ? 24 : t2_, col, grp);

        unsigned long long XA0, XA1, XA2, XA3, XB0, XB1, XB2, XB3;
        XA0 = *(const unsigned long long*)(x0p + 4 * uD0);
        XA1 = *(const unsigned long long*)(x0p + 4 * uD1);
        XA2 = *(const unsigned long long*)(x0p + 4 * uD2);
        XA3 = *(const unsigned long long*)(x0p + 4 * uD3);
        XB0 = *(const unsigned long long*)(x0p + 400 + 4 * uD0);
        XB1 = *(const unsigned long long*)(x0p + 400 + 4 * uD1);
        XB2 = *(const unsigned long long*)(x0p + 400 + 4 * uD2);
        XB3 = *(const unsigned long long*)(x0p + 400 + 4 * uD3);

        if (j < 128) lds[j] = 0u;  // h0(-1)=0 + K-pad, both records
        float c0 = 0.f, hv = 0.f;
        __syncthreads();

#define B0TICK(T_, P_, X0_, X1_, X2_, X3_) do {                                              \
    f32x4 ci0_ = xcvt(X0_), ci1_ = xcvt(X1_), ci2_ = xcvt(X2_), ci3_ = xcvt(X3_);            \
    {                                                                                        \
        int tn_ = (T_) + 2 < T_STEPS ? (T_) + 2 : T_STEPS - 1;                               \
        const _Float16* xb_ = x0p + (size_t)tn_ * 400;                                       \
        X0_ = *(const unsigned long long*)(xb_ + 4 * uD0);                                   \
        X1_ = *(const unsigned long long*)(xb_ + 4 * uD1);                                   \
        X2_ = *(const unsigned long long*)(xb_ + 4 * uD2);                                   \
        X3_ = *(const unsigned long long*)(xb_ + 4 * uD3);                                   \
    }                                                                                        \
    SCAN_CORE(P_, ci0_, ci1_, ci2_, ci3_, c0, hv);                                           \
    if ((T_) == T_STEPS - 1 && (l & 15) < 4) { outTail[uS] = hv; outTail[200 + uS] = c0; }   \
    if (wid == 7 && l < 50) {                                                                \
        if ((T_) >= 1) AST(&h0seq[(size_t)((T_) - 1) * 50 + l], lds[(P_) * 64 + l]);         \
        if (l == 0 && (((T_) & 7) == 7)) ASTR(&flags[0], (unsigned)(T_));                    \
    }                                                                                        \
    bar_lds();                                                                               \
} while (0)

        for (int t = 0; t < T_STEPS; t += 2) {
            B0TICK(t, 0, XA0, XA1, XA2, XA3);
            B0TICK(t + 1, 1, XB0, XB1, XB2, XB3);
        }
        // final h0(T-1) sits in record 0
        if (wid == 7 && l < 50) {
            AST(&h0seq[(size_t)(T_STEPS - 1) * 50 + l], lds[l]);
            if (l == 0) ASTR(&flags[0], (unsigned)T_STEPS);
        }
#undef B0TICK
    } else if (blockIdx.x == 1) {
        // ---------------- Bz: z1 streaming GEMM (round-9 VERBATIM) ----------------
        const int q = j & 3, u = j >> 2, H = q & 1, gA = (q >> 1) * 2;
        const int hoff = H * 112;
        h2 wA[25], wB[25];
        float bz = 0.f;
        if (j < 400) {
            int r0 = gA * 100 + u;
            ldw(wA, Wih1 + r0 * 100 + 50 * H);
            ldw(wB, Wih1 + (r0 + 100) * 100 + 50 * H);
            int ro = q * 100 + u;
            bz = bih1[ro] + bhh1[ro];
        }
        for (int idx = j; idx < 896; idx += 512) lds[idx] = 0u;
        __syncthreads();

        unsigned fcache = 0, bpc = 0;
        for (int tau = 0; tau < 2048; ++tau) {
            const int t0 = tau * 16;
            while (fcache < (unsigned)(t0 + 16)) {
                fcache = ALD(&flags[0]);
                if (fcache < (unsigned)(t0 + 16)) __builtin_amdgcn_s_sleep(8);
            }
            int lim = t0 + 32 - (RMASK + 1);  // ring backpressure (round-7 fix)
            if (lim > 0) {
                while ((int)bpc < lim) {
                    bpc = ALD(&flags[2]);
                    if ((int)bpc < lim) __builtin_amdgcn_s_sleep(8);
                }
            }
            CFENCE();
            for (int g = j; g < 800; g += 512) {
                int tt = g / 50, k = g % 50;
                lds[tt * 56 + ((k < 25) ? k : k + 3)] = ALD(&h0seq[(size_t)t0 * 50 + g]);
            }
            __syncthreads();
            if (j < 400) {
                for (int tt = 0; tt < 16; ++tt) {
                    float2 p = mv25(wA, wB, (const char*)(lds + tt * 56) + hoff);
                    float pA = p.x + qperm<0xB1>(p.x);
                    float pB = p.y + qperm<0xB1>(p.y);
                    AST((unsigned*)&z1ring[(size_t)((t0 + tt) & RMASK) * 400 + j],
                        __builtin_bit_cast(unsigned, (H ? pB : pA) + bz));
                }
            }
            __syncthreads();
            if (j == 0) ASTR(&flags[1], (unsigned)(tau + 1));
        }
    } else {
        // ---------------- B2: layer-1 MFMA scan ----------------
        const int wid = j >> 6, l = j & 63, col = l & 15, grp = l >> 4, lsel = l & 3;
        const int t0_ = wid, t1_ = wid + 8, t2_ = wid + 16;
        const int uD0 = 4 * t0_ + grp, uD1 = 4 * t1_ + grp, uD2 = 4 * t2_ + grp;
        const int uD3 = 96 + grp;
        int tsel;
        if (wid == 0) tsel = (lsel == 0) ? t0_ : ((lsel == 1) ? t1_ : ((lsel == 2) ? t2_ : 24));
        else          tsel = (lsel == 0) ? t0_ : ((lsel == 1) ? t1_ : t2_);
        const int uS = 4 * tsel + grp;

        f16x8 w0[4], w1[4], w2[4], w3[4];
        packA(w0, Whh1, t0_, col, grp);
        packA(w1, Whh1, t1_, col, grp);
        packA(w2, Whh1, t2_, col, grp);
        packA(w3, Whh1, (wid == 0) ? 24 : t2_, col, grp);

        if (j < 128) lds[j] = 0u;  // h1(-1)=0 + K-pad
        float c1 = 0.f, hv = 0.f;
        unsigned zdc = 0;
        __syncthreads();
        if (j == 448) {  // wait for z tile 0 (ticks 0..15)
            while ((zdc = ALD(&flags[1])) < 1u) __builtin_amdgcn_s_sleep(8);
            CFENCE();
        }
        __syncthreads();

        // z prefetch regs: f32x4 per tile, two parities (agent-scope u32 loads)
        f32x4 ZA0, ZA1, ZA2, ZA3, ZB0, ZB1, ZB2, ZB3;
#define ZLOAD(D_, TK_, UD_) do {                                                             \
    const unsigned* zp_ = (const unsigned*)z1ring + (size_t)((TK_) & RMASK) * 400 + 4 * (UD_);\
    D_[0] = __builtin_bit_cast(float, ALD(zp_ + 0));                                         \
    D_[1] = __builtin_bit_cast(float, ALD(zp_ + 1));                                         \
    D_[2] = __builtin_bit_cast(float, ALD(zp_ + 2));                                         \
    D_[3] = __builtin_bit_cast(float, ALD(zp_ + 3));                                         \
} while (0)
        ZLOAD(ZA0, 0, uD0); ZLOAD(ZA1, 0, uD1); ZLOAD(ZA2, 0, uD2); ZLOAD(ZA3, 0, uD3);
        ZLOAD(ZB0, 1, uD0); ZLOAD(ZB1, 1, uD1); ZLOAD(ZB2, 1, uD2); ZLOAD(ZB3, 1, uD3);

#define B2TICK(T_, P_, Z0_, Z1_, Z2_, Z3_) do {                                              \
    f32x4 ci0_ = Z0_, ci1_ = Z1_, ci2_ = Z2_, ci3_ = Z3_;                                    \
    {                                                                                        \
        int tn_ = (T_) + 2 < T_STEPS ? (T_) + 2 : T_STEPS - 1;                               \
        ZLOAD(Z0_, tn_, uD0); ZLOAD(Z1_, tn_, uD1);                                          \
        ZLOAD(Z2_, tn_, uD2); ZLOAD(Z3_, tn_, uD3);                                          \
    }                                                                                        \
    SCAN_CORE(P_, ci0_, ci1_, ci2_, ci3_, c1, hv);                                           \
    if ((l & 15) < 4) {                                                                      \
        h1s[(size_t)(T_) * 100 + uS] = hv;                                                   \
        if ((T_) == T_STEPS - 1) { outTail[100 + uS] = hv; outTail[300 + uS] = c1; }         \
    }                                                                                        \
    if (j == 448) {                                                                          \
        int tq_ = (T_) + 3 < T_STEPS ? (T_) + 3 : T_STEPS - 1;                               \
        unsigned need_ = (unsigned)(tq_ >> 4) + 1u;                                          \
        if (zdc < need_) {                                                                   \
            while ((zdc = ALD(&flags[1])) < need_) __builtin_amdgcn_s_sleep(2);              \
            CFENCE();                                                                        \
        }                                                                                    \
        if (((T_) & 255) == 255) ASTR(&flags[2], (unsigned)(T_) + 1u);                       \
    }                                                                                        \
    bar_lds();                                                                               \
} while (0)

        for (int t = 0; t < T_STEPS; t += 2) {
            B2TICK(t, 0, ZA0, ZA1, ZA2, ZA3);
            B2TICK(t + 1, 1, ZB0, ZB1, ZB2, ZB3);
        }
#undef B2TICK
#undef ZLOAD
    }
}

// ---------------- C: outputs[t][d] = h1s[t] . W_out[d] + b_out[d] ----------------
__global__ __launch_bounds__(320) void k_out(const float* __restrict__ h1s,
                                             const float* __restrict__ Wout,
                                             const float* __restrict__ bout,
                                             float* __restrict__ out) {
    __shared__ float hs[32 * 100];
    int t0 = blockIdx.x * 32;
    for (int idx = threadIdx.x; idx < 3200; idx += 320) hs[idx] = h1s[(size_t)t0 * 100 + idx];
    __syncthreads();
    int d = threadIdx.x;
    if (d < 300) {
        float acc[32];
#pragma unroll
        for (int i = 0; i < 32; i++) acc[i] = 0.f;
        const float4* w4 = (const float4*)(Wout + d * 100);
        const float4* h4 = (const float4*)hs;
        for (int j4 = 0; j4 < 25; j4++) {
            float4 w = w4[j4];
#pragma unroll
            for (int ti = 0; ti < 32; ti++) {
                float4 h = h4[ti * 25 + j4];
                acc[ti] += w.x * h.x + w.y * h.y + w.z * h.z + w.w * h.w;
            }
        }
        float bb = bout[d];
#pragma unroll
        for (int ti = 0; ti < 32; ti++) out[(size_t)(t0 + ti) * 300 + d] = acc[ti] + bb;
    }
}

extern "C" void kernel_launch(void* const* d_in, const int* in_sizes, int n_in,
                              void* d_out, int out_size, void* d_ws, size_t ws_size,
                              hipStream_t stream) {
    const float* inputs = (const float*)d_in[0];
    const float* W_inp  = (const float*)d_in[1];
    const float* b_inp  = (const float*)d_in[2];
    const float* W_ih0  = (const float*)d_in[3];
    const float* W_hh0  = (const float*)d_in[4];
    const float* b_ih0  = (const float*)d_in[5];
    const float* b_hh0  = (const float*)d_in[6];
    const float* W_ih1  = (const float*)d_in[7];
    const float* W_hh1  = (const float*)d_in[8];
    const float* b_ih1  = (const float*)d_in[9];
    const float* b_hh1  = (const float*)d_in[10];
    const float* W_out  = (const float*)d_in[11];
    const float* b_out  = (const float*)d_in[12];
    float* out = (float*)d_out;

    char* ws = (char*)d_ws;
    _Float16* x0p = (_Float16*)ws;                    // 32768*400*2 = 26,214,400 B
    float* h1s = (float*)(ws + 26214400);             // 32768*100*4 = 13,107,200 B
    float* Wc  = (float*)(ws + 26214400 + 13107200);  // 400*300*4   =    480,000 B
    float* bc  = Wc + 120000;                         // 400*4 B

    // out-scratch region [0, OUT_BASE*4): fully overwritten by k_out afterwards.
    float*    z1ring = out;                                   // 26,214,400 B
    unsigned* h0seq  = (unsigned*)((char*)out + 26214400);    //  6,553,600 B
    unsigned* flagsp = (unsigned*)((char*)out + 32768000);    //  3 u32
    float*    outTail = out + OUT_BASE;

    hipMemsetAsync(flagsp, 0, 16, stream);
    k_precomp<<<471, 256, 0, stream>>>(W_inp, b_inp, W_ih0, b_ih0, b_hh0, Wc, bc);
    k_xproj<<<1024, 512, 0, stream>>>(inputs, Wc, bc, x0p);

    void* args[] = {(void*)&x0p, (void*)&W_hh0, (void*)&W_ih1, (void*)&W_hh1,
                    (void*)&b_ih1, (void*)&b_hh1, (void*)&h1s, (void*)&outTail,
                    (void*)&h0seq, (void*)&z1ring, (void*)&flagsp};
    hipLaunchCooperativeKernel((void*)k_scan3, dim3(3), dim3(512), args, 0, stream);

    k_out<<<1024, 320, 0, stream>>>(h1s, W_out, b_out, out);
}